// Round 7
// baseline (161.841 us; speedup 1.0000x reference)
//
#include <hip/hip_runtime.h>
#include <math.h>

// Problem constants (fixed by the reference's setup_inputs)
#define T_STEPS 16
#define BB      128
#define VOCAB   32000
#define V4      (VOCAB / 4)   // 8000 float4 per row
#define BEAM    4
#define BATCH   (BB / BEAM)   // 32
#define TAU     2.75f         // survivor threshold: E[survivors/row] ~ 96

// ---------------------------------------------------------------------------
// Total-order comparator matching jax.lax.top_k: value descending, index
// ascending on ties. (a ranks before b)?
__device__ __forceinline__ bool gtvi(float av, int ai, float bv, int bi) {
    return (av > bv) || (av == bv && ai < bi);
}

// Insert (x, gi) into a sorted-descending top-8 list (fallback/merge paths).
__device__ __forceinline__ void ins8(float (&v)[8], int (&ix)[8], float x, int gi) {
    if (gtvi(x, gi, v[7], ix[7])) {
        v[7] = x; ix[7] = gi;
#pragma unroll
        for (int j = 7; j > 0; --j) {
            if (gtvi(v[j], ix[j], v[j - 1], ix[j - 1])) {
                float tv = v[j]; v[j] = v[j - 1]; v[j - 1] = tv;
                int   ti = ix[j]; ix[j] = ix[j - 1]; ix[j - 1] = ti;
            }
        }
    }
}

// 19-comparator sorting network (Batcher, n=8), descending under gtvi.
__device__ __forceinline__ void sort8(float (&v)[8], int (&ix)[8]) {
#define CE(a, b)                                                              \
    if (gtvi(v[b], ix[b], v[a], ix[a])) {                                     \
        float tv = v[a]; v[a] = v[b]; v[b] = tv;                              \
        int   ti = ix[a]; ix[a] = ix[b]; ix[b] = ti;                          \
    }
    CE(0,1) CE(2,3) CE(4,5) CE(6,7)
    CE(0,2) CE(1,3) CE(4,6) CE(5,7)
    CE(1,2) CE(5,6) CE(0,4) CE(3,7)
    CE(1,5) CE(2,6)
    CE(1,4) CE(3,6)
    CE(2,4) CE(3,5)
    CE(3,4)
#undef CE
}

// Wave(64)-level butterfly merge of per-lane sorted-desc 8-lists.
__device__ __forceinline__ void wave_merge8(float (&v)[8], int (&ix)[8]) {
#pragma unroll
    for (int m = 1; m < 64; m <<= 1) {
        float u[8]; int ju[8];
#pragma unroll
        for (int k = 0; k < 8; ++k) {
            u[k]  = __shfl_xor(v[k],  m, 64);
            ju[k] = __shfl_xor(ix[k], m, 64);
        }
        float w[8]; int jw[8];
#pragma unroll
        for (int k = 0; k < 8; ++k) {
            if (gtvi(u[7 - k], ju[7 - k], v[k], ix[k])) { w[k] = u[7 - k]; jw[k] = ju[7 - k]; }
            else                                        { w[k] = v[k];     jw[k] = ix[k];     }
        }
#define CE_DESC(a, b)                                                         \
        if (gtvi(w[b], jw[b], w[a], jw[a])) {                                 \
            float tv = w[a]; w[a] = w[b]; w[b] = tv;                          \
            int   ti = jw[a]; jw[a] = jw[b]; jw[b] = ti;                      \
        }
        CE_DESC(0, 4) CE_DESC(1, 5) CE_DESC(2, 6) CE_DESC(3, 7)
        CE_DESC(0, 2) CE_DESC(1, 3) CE_DESC(4, 6) CE_DESC(5, 7)
        CE_DESC(0, 1) CE_DESC(2, 3) CE_DESC(4, 5) CE_DESC(6, 7)
#undef CE_DESC
#pragma unroll
        for (int k = 0; k < 8; ++k) { v[k] = w[k]; ix[k] = jw[k]; }
    }
}

// ---------------------------------------------------------------------------
// Phase 1: per (step,row): sum(exp(x)) + exact top-8 of x excluding pad/unk.
// Hot path: copy-free depth-4 double-buffered streaming — two 4-buffer
// groups alternate in straight-line code, so one group's 4 KB/wave of loads
// is ALWAYS in flight while the other group is processed (no register-copy
// drain). Survivors (>TAU) appended unsorted to a register top-8; sorted
// once post-stream. <8 valid survivors or overflow -> exact full rescan.
__global__ __launch_bounds__(256, 4) void phase1_topk_lsm(
    const float* __restrict__ logits,
    const int*   __restrict__ pad_p,
    const int*   __restrict__ unk_p,
    float* __restrict__ topv,
    int*   __restrict__ topi)
{
    __shared__ float s_red[4];
    __shared__ int   s_icnt[4];
    __shared__ float s_mv[32];
    __shared__ int   s_mi[32];
    __shared__ float s_logS;
    __shared__ int   s_tot;

    const int row = blockIdx.x;            // t*BB + r
    const int tid = threadIdx.x;
    const int pad = *pad_p, unk = *unk_p;
    const float4* __restrict__ src =
        reinterpret_cast<const float4*>(logits + (size_t)row * VOCAB);

    float v[8]; int ix[8];
#pragma unroll
    for (int k = 0; k < 8; ++k) { v[k] = -INFINITY; ix[k] = 0x7FFFFFFF; }
    float tsum = 0.0f;
    int   c = 0, ovf = 0;                  // appended survivors / overflow flag

    auto process = [&](float4 q, int gi) {   // gi = word index of q.x
        tsum += (__expf(q.x) + __expf(q.y)) + (__expf(q.z) + __expf(q.w));
        const float mx = fmaxf(fmaxf(q.x, q.y), fmaxf(q.z, q.w));
        if (__builtin_expect(mx > TAU, 0)) {
            int cnt4 = (q.x > TAU) + (q.y > TAU) + (q.z > TAU) + (q.w > TAU);
            float a0 = q.x, a1 = q.y, a2 = q.z, a3 = q.w;
            do {
                // extract current max, preferring lower component index
                float m0 = a0; int id = 0;
                if (a1 > m0) { m0 = a1; id = 1; }
                if (a2 > m0) { m0 = a2; id = 2; }
                if (a3 > m0) { m0 = a3; id = 3; }
                const int w = gi + id;
                if (w != pad && w != unk) {
                    switch (c) {           // static-index append (no scratch)
                        case 0: v[0] = m0; ix[0] = w; break;
                        case 1: v[1] = m0; ix[1] = w; break;
                        case 2: v[2] = m0; ix[2] = w; break;
                        case 3: v[3] = m0; ix[3] = w; break;
                        case 4: v[4] = m0; ix[4] = w; break;
                        case 5: v[5] = m0; ix[5] = w; break;
                        case 6: v[6] = m0; ix[6] = w; break;
                        case 7: v[7] = m0; ix[7] = w; break;
                        default: ovf = 1; break;
                    }
                    ++c;
                }
                if      (id == 0) a0 = -INFINITY;
                else if (id == 1) a1 = -INFINITY;
                else if (id == 2) a2 = -INFINITY;
                else              a3 = -INFINITY;
            } while (--cnt4 > 0);
        }
    };

    // ---- copy-free depth-4 double-buffered hot loop ----
    // 7 groups of 4 strided iters (offsets 0..7167) alternate between
    // register groups a* and c*; then 3 strided iters + 64-thread tail.
#define LOAD4(B, OFF)                                                         \
    do {                                                                      \
        B##0 = src[(OFF) + tid];                                              \
        B##1 = src[(OFF) + tid + 256];                                        \
        B##2 = src[(OFF) + tid + 512];                                        \
        B##3 = src[(OFF) + tid + 768];                                        \
        __builtin_amdgcn_sched_barrier(0);                                    \
    } while (0)
#define PROC4(B, OFF)                                                         \
    do {                                                                      \
        process(B##0, ((OFF) + tid) * 4);                                     \
        process(B##1, ((OFF) + tid + 256) * 4);                               \
        process(B##2, ((OFF) + tid + 512) * 4);                               \
        process(B##3, ((OFF) + tid + 768) * 4);                               \
    } while (0)

    float4 a0, a1, a2, a3, c0, c1, c2, c3;
    LOAD4(a, 0);
    LOAD4(c, 1024);
    PROC4(a, 0);    LOAD4(a, 2048);
    PROC4(c, 1024); LOAD4(c, 3072);
    PROC4(a, 2048); LOAD4(a, 4096);
    PROC4(c, 3072); LOAD4(c, 5120);
    PROC4(a, 4096); LOAD4(a, 6144);
    PROC4(c, 5120);
    PROC4(a, 6144);

    {   // tail: offsets 7168, 7424, 7680 (all threads) + 7936 (tid<64)
        float4 t0 = src[7168 + tid];
        float4 t1 = src[7424 + tid];
        float4 t2 = src[7680 + tid];
        const bool ht = (tid < 64);
        float4 t3;
        if (ht) t3 = src[7936 + tid];
        __builtin_amdgcn_sched_barrier(0);
        process(t0, (7168 + tid) * 4);
        process(t1, (7424 + tid) * 4);
        process(t2, (7680 + tid) * 4);
        if (ht) process(t3, (7936 + tid) * 4);
    }
#undef LOAD4
#undef PROC4

    // ---- block reductions: exp-sum + valid-survivor count (ovf poisons) ----
    int cc = ovf ? -65536 : c;
#pragma unroll
    for (int m = 1; m < 64; m <<= 1) {
        tsum += __shfl_xor(tsum, m, 64);
        cc   += __shfl_xor(cc,   m, 64);
    }
    const int wv = tid >> 6, ln = tid & 63;
    if (ln == 0) { s_red[wv] = tsum; s_icnt[wv] = cc; }
    __syncthreads();
    if (tid == 0) {
        s_logS = logf((s_red[0] + s_red[1]) + (s_red[2] + s_red[3]));
        s_tot  = (s_icnt[0] + s_icnt[1]) + (s_icnt[2] + s_icnt[3]);
    }
    __syncthreads();
    const float logS = s_logS;

    if (s_tot >= 8) {
        sort8(v, ix);                      // unsorted appends -> sorted desc
    } else {
        // ---- exact fallback (never for N(0,1) rows): full rescan ----
#pragma unroll
        for (int k = 0; k < 8; ++k) { v[k] = -INFINITY; ix[k] = 0x7FFFFFFF; }
        for (int k2 = tid; k2 < V4; k2 += 256) {
            float4 f = src[k2];
            const int gi = k2 * 4;
            if ((gi + 0) != pad && (gi + 0) != unk) ins8(v, ix, f.x, gi + 0);
            if ((gi + 1) != pad && (gi + 1) != unk) ins8(v, ix, f.y, gi + 1);
            if ((gi + 2) != pad && (gi + 2) != unk) ins8(v, ix, f.z, gi + 2);
            if ((gi + 3) != pad && (gi + 3) != unk) ins8(v, ix, f.w, gi + 3);
        }
    }

    // ---- merge: wave butterfly, then cross-wave via LDS ----
    wave_merge8(v, ix);
    if (ln == 0) {
#pragma unroll
        for (int k = 0; k < 8; ++k) { s_mv[wv * 8 + k] = v[k]; s_mi[wv * 8 + k] = ix[k]; }
    }
    __syncthreads();
    if (tid == 0) {
        float bv[8]; int bi[8];
#pragma unroll
        for (int k = 0; k < 8; ++k) { bv[k] = -INFINITY; bi[k] = 0x7FFFFFFF; }
        for (int j = 0; j < 32; ++j) ins8(bv, bi, s_mv[j], s_mi[j]);
        float* ov = topv + (size_t)row * 8;
        int*   oi = topi + (size_t)row * 8;
#pragma unroll
        for (int k = 0; k < 8; ++k) { ov[k] = bv[k] - logS; oi[k] = bi[k]; }
    }
}

// ---------------------------------------------------------------------------
// Phase 2: 16-step beam scan, one wave per batch, fully wave-parallel.
// All candidates preloaded to LDS once; per step a 64-lane bitonic sort by
// (val desc, cand-idx asc) gives the exact top-8, then an 8-lane mini-sort
// after eos masking gives the exact top_k(masked, 4).
__global__ __launch_bounds__(64) void phase2_beam_scan(
    const float* __restrict__ topv,
    const int*   __restrict__ topi,
    const int*   __restrict__ eos_p,
    float* __restrict__ out)
{
    const int b    = blockIdx.x;   // batch index
    const int lane = threadIdx.x;  // 0..63, single wave
    const int eos  = *eos_p;

    __shared__ float s_v[T_STEPS][32];
    __shared__ int   s_w[T_STEPS][32];
    __shared__ float s_sc[BEAM];
    __shared__ int   s_rb[T_STEPS][BEAM];
    __shared__ int   s_rw[T_STEPS][BEAM];

    for (int g = lane; g < T_STEPS * 32; g += 64) {
        const int t = g >> 5, j = g & 31;
        const size_t off = (size_t)t * (BB * 8) + (size_t)b * (BEAM * 8) + j;
        s_v[t][j] = topv[off];
        s_w[t][j] = topi[off];
    }
    if (lane < BEAM) s_sc[lane] = 0.0f;
    __syncthreads();

    for (int t = 0; t < T_STEPS; ++t) {
        float val; int word, cj;
        if (lane < 32) {
            cj   = lane;                       // beam*8 + pos
            word = s_w[t][lane];
            val  = s_v[t][lane] + s_sc[lane >> 3];
        } else {
            cj = 64 + lane; word = 0; val = -INFINITY;
        }

        // ---- 64-lane bitonic sort, descending by (val, cj asc) ----
#pragma unroll
        for (int k = 2; k <= 64; k <<= 1) {
#pragma unroll
            for (int j = k >> 1; j > 0; j >>= 1) {
                const float ov = __shfl_xor(val,  j, 64);
                const int   oc = __shfl_xor(cj,   j, 64);
                const int   ow = __shfl_xor(word, j, 64);
                const bool dirDesc   = ((lane & k) == 0);
                const bool iAmLow    = ((lane & j) == 0);
                const bool mineFirst = gtvi(val, cj, ov, oc);
                const bool takeOther = dirDesc ? (iAmLow ? !mineFirst : mineFirst)
                                               : (iAmLow ? mineFirst : !mineFirst);
                if (takeOther) { val = ov; cj = oc; word = ow; }
            }
        }

        // ---- lanes 0..7 = top-8 desc. eos mask, then exact top_k(masked,4)
        float mval; int pos = lane, srcb = 0, w8 = 0;
        if (lane < 8) {
            w8   = word;
            srcb = cj >> 3;
            const bool iseos = (w8 == eos) && (val > -INFINITY);
            mval = iseos ? -INFINITY : val;
        } else {
            mval = -INFINITY;
        }
#pragma unroll
        for (int k = 2; k <= 8; k <<= 1) {
#pragma unroll
            for (int j = k >> 1; j > 0; j >>= 1) {
                const float ov = __shfl_xor(mval, j, 64);
                const int   op = __shfl_xor(pos,  j, 64);
                const int   ob = __shfl_xor(srcb, j, 64);
                const int   ow = __shfl_xor(w8,   j, 64);
                const bool dirDesc   = ((lane & k) == 0);
                const bool iAmLow    = ((lane & j) == 0);
                const bool mineFirst = gtvi(mval, pos, ov, op);
                const bool takeOther = dirDesc ? (iAmLow ? !mineFirst : mineFirst)
                                               : (iAmLow ? mineFirst : !mineFirst);
                if (takeOther) { mval = ov; pos = op; srcb = ob; w8 = ow; }
            }
        }

        if (lane < 4) {
            s_sc[lane]    = mval;   // new cumulative scores (sel_scores)
            s_rb[t][lane] = srcb;   // source (old) beam
            s_rw[t][lane] = w8;     // chosen word
        }
        __syncthreads();
    }

    // Backtrace + output (d_out = [scores (128) | tokens (128*17)], f32)
    if (lane < BEAM) {
        out[b * BEAM + lane] = s_sc[lane];
        float* tout = out + BATCH * BEAM + (size_t)(b * BEAM + lane) * (T_STEPS + 1);
        int bp = lane;
#pragma unroll
        for (int t = T_STEPS - 1; t >= 0; --t) {
            tout[t + 1] = (float)s_rw[t][bp];
            bp = s_rb[t][bp];
        }
        tout[0] = (float)eos;   // begin token
    }
}

// ---------------------------------------------------------------------------
extern "C" void kernel_launch(void* const* d_in, const int* in_sizes, int n_in,
                              void* d_out, int out_size, void* d_ws, size_t ws_size,
                              hipStream_t stream) {
    const float* logits = (const float*)d_in[0];
    const int*   pad_p  = (const int*)d_in[1];
    const int*   unk_p  = (const int*)d_in[2];
    const int*   eos_p  = (const int*)d_in[3];
    // d_in[4] = beam_size (hardcoded 4 to match shapes)

    // Workspace: topv [T*BB*8] f32, then topi [T*BB*8] i32  (128 KB total)
    float* topv = (float*)d_ws;
    int*   topi = (int*)(topv + T_STEPS * BB * 8);

    hipLaunchKernelGGL(phase1_topk_lsm, dim3(T_STEPS * BB), dim3(256), 0, stream,
                       logits, pad_p, unk_p, topv, topi);
    hipLaunchKernelGGL(phase2_beam_scan, dim3(BATCH), dim3(64), 0, stream,
                       topv, topi, eos_p, (float*)d_out);
}

// Round 8
// 110.732 us; speedup vs baseline: 1.4616x; 1.4616x over previous
//
#include <hip/hip_runtime.h>
#include <math.h>

// Problem constants (fixed by the reference's setup_inputs)
#define T_STEPS 16
#define BB      128
#define VOCAB   32000
#define V4      (VOCAB / 4)   // 8000 float4 per row
#define BEAM    4
#define BATCH   (BB / BEAM)   // 32
#define NROWS   (T_STEPS * BB)        // 2048
#define TAU     3.0f          // survivor threshold: E[survivors/row] ~ 43
#define CAP_S   128           // per-row survivor capacity (12.9 sigma margin)
#define CHUNK_F4 2000         // float4 per stream block (4 blocks/row)

// ---------------------------------------------------------------------------
// Total-order comparator matching jax.lax.top_k: value descending, index
// ascending on ties. (a ranks before b)?
__device__ __forceinline__ bool gtvi(float av, int ai, float bv, int bi) {
    return (av > bv) || (av == bv && ai < bi);
}

// Insert (x, gi) into a sorted-descending top-8 list held in registers.
__device__ __forceinline__ void ins8(float (&v)[8], int (&ix)[8], float x, int gi) {
    if (gtvi(x, gi, v[7], ix[7])) {
        v[7] = x; ix[7] = gi;
#pragma unroll
        for (int j = 7; j > 0; --j) {
            if (gtvi(v[j], ix[j], v[j - 1], ix[j - 1])) {
                float tv = v[j]; v[j] = v[j - 1]; v[j - 1] = tv;
                int   ti = ix[j]; ix[j] = ix[j - 1]; ix[j - 1] = ti;
            }
        }
    }
}

// Wave(64)-level butterfly merge of per-lane sorted-desc 8-lists.
__device__ __forceinline__ void wave_merge8(float (&v)[8], int (&ix)[8]) {
#pragma unroll
    for (int m = 1; m < 64; m <<= 1) {
        float u[8]; int ju[8];
#pragma unroll
        for (int k = 0; k < 8; ++k) {
            u[k]  = __shfl_xor(v[k],  m, 64);
            ju[k] = __shfl_xor(ix[k], m, 64);
        }
        float w[8]; int jw[8];
#pragma unroll
        for (int k = 0; k < 8; ++k) {
            if (gtvi(u[7 - k], ju[7 - k], v[k], ix[k])) { w[k] = u[7 - k]; jw[k] = ju[7 - k]; }
            else                                        { w[k] = v[k];     jw[k] = ix[k];     }
        }
#define CE_DESC(a, b)                                                         \
        if (gtvi(w[b], jw[b], w[a], jw[a])) {                                 \
            float tv = w[a]; w[a] = w[b]; w[b] = tv;                          \
            int   ti = jw[a]; jw[a] = jw[b]; jw[b] = ti;                      \
        }
        CE_DESC(0, 4) CE_DESC(1, 5) CE_DESC(2, 6) CE_DESC(3, 7)
        CE_DESC(0, 2) CE_DESC(1, 3) CE_DESC(4, 6) CE_DESC(5, 7)
        CE_DESC(0, 1) CE_DESC(2, 3) CE_DESC(4, 5) CE_DESC(6, 7)
#undef CE_DESC
#pragma unroll
        for (int k = 0; k < 8; ++k) { v[k] = w[k]; ix[k] = jw[k]; }
    }
}

// ---------------------------------------------------------------------------
// Kernel A: streaming pass. 4 blocks per row (8192 blocks x 256 threads).
// Per thread: 8 unconditional burst float4 loads, then exp-sum + rare
// threshold-survivor append to a global per-row list. Partial exp-sums go
// to sums4[row][chunk] (fixed combine order in kernel B -> deterministic).
__global__ __launch_bounds__(256) void stream_scan(
    const float* __restrict__ logits,
    const int*   __restrict__ pad_p,
    const int*   __restrict__ unk_p,
    float* __restrict__ sv,     // [NROWS][CAP_S] survivor values
    int*   __restrict__ si,     // [NROWS][CAP_S] survivor words
    int*   __restrict__ cnt,    // [NROWS] survivor counts (pre-zeroed)
    float* __restrict__ sums4)  // [NROWS][4] partial exp-sums
{
    __shared__ float s_red[4];

    const int bid   = blockIdx.x;
    const int row   = bid >> 2;
    const int chunk = bid & 3;
    const int tid   = threadIdx.x;
    const int pad   = *pad_p, unk = *unk_p;
    const int rowb  = row * CAP_S;
    const int wchunk = chunk * CHUNK_F4;   // first float4 index of this chunk
    const float4* __restrict__ src =
        reinterpret_cast<const float4*>(logits + (size_t)row * VOCAB) + wchunk;

    // ---- 8 burst loads, no branches in between ----
    // k=0..6 cover float4 0..1791 (all valid); k=7 covers 1792..1999
    // (valid iff tid<208; clamped duplicate load otherwise, excluded below).
    const bool v7 = (tid < 208);
    const int  i7 = 1792 + (v7 ? tid : 207);
    float4 r0 = src[tid];
    float4 r1 = src[tid + 256];
    float4 r2 = src[tid + 512];
    float4 r3 = src[tid + 768];
    float4 r4 = src[tid + 1024];
    float4 r5 = src[tid + 1280];
    float4 r6 = src[tid + 1536];
    float4 r7 = src[i7];

    float tsum = 0.0f;

    auto do4 = [&](float4 q, int wbase) {   // wbase = global word idx of q.x
        tsum += (__expf(q.x) + __expf(q.y)) + (__expf(q.z) + __expf(q.w));
        const float mx = fmaxf(fmaxf(q.x, q.y), fmaxf(q.z, q.w));
        if (__builtin_expect(mx > TAU, 0)) {
            const bool s0 = q.x > TAU && (wbase + 0) != pad && (wbase + 0) != unk;
            const bool s1 = q.y > TAU && (wbase + 1) != pad && (wbase + 1) != unk;
            const bool s2 = q.z > TAU && (wbase + 2) != pad && (wbase + 2) != unk;
            const bool s3 = q.w > TAU && (wbase + 3) != pad && (wbase + 3) != unk;
            const int c4 = (int)s0 + (int)s1 + (int)s2 + (int)s3;
            if (c4) {
                int p = atomicAdd(&cnt[row], c4);
                if (s0) { if (p < CAP_S) { sv[rowb + p] = q.x; si[rowb + p] = wbase + 0; } ++p; }
                if (s1) { if (p < CAP_S) { sv[rowb + p] = q.y; si[rowb + p] = wbase + 1; } ++p; }
                if (s2) { if (p < CAP_S) { sv[rowb + p] = q.z; si[rowb + p] = wbase + 2; } ++p; }
                if (s3) { if (p < CAP_S) { sv[rowb + p] = q.w; si[rowb + p] = wbase + 3; } ++p; }
            }
        }
    };

    const int wb0 = (wchunk + tid) * 4;    // word index of r0.x
    do4(r0, wb0);
    do4(r1, wb0 + 1024);
    do4(r2, wb0 + 2048);
    do4(r3, wb0 + 3072);
    do4(r4, wb0 + 4096);
    do4(r5, wb0 + 5120);
    do4(r6, wb0 + 6144);
    if (v7) do4(r7, (wchunk + i7) * 4);

    // ---- block reduction of partial exp-sum -> sums4[row][chunk] ----
#pragma unroll
    for (int m = 1; m < 64; m <<= 1) tsum += __shfl_xor(tsum, m, 64);
    const int wv = tid >> 6, ln = tid & 63;
    if (ln == 0) s_red[wv] = tsum;
    __syncthreads();
    if (tid == 0)
        sums4[row * 4 + chunk] = (s_red[0] + s_red[1]) + (s_red[2] + s_red[3]);
}

// ---------------------------------------------------------------------------
// Kernel B: per-row selection. One wave per row. Exact top-8 of the survivor
// list (order-independent via total-order comparator), normalized by the
// deterministic fixed-order logS. Fallback: exact full-row rescan if the
// survivor list under/overflowed (never for N(0,1) rows).
__global__ __launch_bounds__(64) void select_topk(
    const float* __restrict__ logits,
    const int*   __restrict__ pad_p,
    const int*   __restrict__ unk_p,
    const float* __restrict__ sv,
    const int*   __restrict__ si,
    const int*   __restrict__ cnt,
    const float* __restrict__ sums4,
    float* __restrict__ topv,
    int*   __restrict__ topi)
{
    const int row  = blockIdx.x;
    const int lane = threadIdx.x;

    const float logS = logf(((sums4[row * 4 + 0] + sums4[row * 4 + 1]) +
                             (sums4[row * 4 + 2] + sums4[row * 4 + 3])));
    const int n = cnt[row];

    float v[8]; int ix[8];
#pragma unroll
    for (int k = 0; k < 8; ++k) { v[k] = -INFINITY; ix[k] = 0x7FFFFFFF; }

    if (n >= 8 && n <= CAP_S) {
        const int rowb = row * CAP_S;
        for (int c = lane; c < n; c += 64) ins8(v, ix, sv[rowb + c], si[rowb + c]);
    } else {
        // exact fallback: full-row scan (wave-parallel)
        const int pad = *pad_p, unk = *unk_p;
        const float4* __restrict__ src =
            reinterpret_cast<const float4*>(logits + (size_t)row * VOCAB);
        for (int kv = lane; kv < V4; kv += 64) {
            float4 q = src[kv];
            const int gi = kv * 4;
            if ((gi + 0) != pad && (gi + 0) != unk) ins8(v, ix, q.x, gi + 0);
            if ((gi + 1) != pad && (gi + 1) != unk) ins8(v, ix, q.y, gi + 1);
            if ((gi + 2) != pad && (gi + 2) != unk) ins8(v, ix, q.z, gi + 2);
            if ((gi + 3) != pad && (gi + 3) != unk) ins8(v, ix, q.w, gi + 3);
        }
    }

    wave_merge8(v, ix);
    if (lane == 0) {
        float* ov = topv + (size_t)row * 8;
        int*   oi = topi + (size_t)row * 8;
#pragma unroll
        for (int k = 0; k < 8; ++k) { ov[k] = v[k] - logS; oi[k] = ix[k]; }
    }
}

// ---------------------------------------------------------------------------
// Phase 2: 16-step beam scan, one wave per batch, fully wave-parallel.
// All candidates preloaded to LDS once; per step a 64-lane bitonic sort by
// (val desc, cand-idx asc) gives the exact top-8, then an 8-lane mini-sort
// after eos masking gives the exact top_k(masked, 4).
__global__ __launch_bounds__(64) void phase2_beam_scan(
    const float* __restrict__ topv,
    const int*   __restrict__ topi,
    const int*   __restrict__ eos_p,
    float* __restrict__ out)
{
    const int b    = blockIdx.x;   // batch index
    const int lane = threadIdx.x;  // 0..63, single wave
    const int eos  = *eos_p;

    __shared__ float s_v[T_STEPS][32];
    __shared__ int   s_w[T_STEPS][32];
    __shared__ float s_sc[BEAM];
    __shared__ int   s_rb[T_STEPS][BEAM];
    __shared__ int   s_rw[T_STEPS][BEAM];

    for (int g = lane; g < T_STEPS * 32; g += 64) {
        const int t = g >> 5, j = g & 31;
        const size_t off = (size_t)t * (BB * 8) + (size_t)b * (BEAM * 8) + j;
        s_v[t][j] = topv[off];
        s_w[t][j] = topi[off];
    }
    if (lane < BEAM) s_sc[lane] = 0.0f;
    __syncthreads();

    for (int t = 0; t < T_STEPS; ++t) {
        float val; int word, cj;
        if (lane < 32) {
            cj   = lane;                       // beam*8 + pos
            word = s_w[t][lane];
            val  = s_v[t][lane] + s_sc[lane >> 3];
        } else {
            cj = 64 + lane; word = 0; val = -INFINITY;
        }

        // ---- 64-lane bitonic sort, descending by (val, cj asc) ----
#pragma unroll
        for (int k = 2; k <= 64; k <<= 1) {
#pragma unroll
            for (int j = k >> 1; j > 0; j >>= 1) {
                const float ov = __shfl_xor(val,  j, 64);
                const int   oc = __shfl_xor(cj,   j, 64);
                const int   ow = __shfl_xor(word, j, 64);
                const bool dirDesc   = ((lane & k) == 0);
                const bool iAmLow    = ((lane & j) == 0);
                const bool mineFirst = gtvi(val, cj, ov, oc);
                const bool takeOther = dirDesc ? (iAmLow ? !mineFirst : mineFirst)
                                               : (iAmLow ? mineFirst : !mineFirst);
                if (takeOther) { val = ov; cj = oc; word = ow; }
            }
        }

        // ---- lanes 0..7 = top-8 desc. eos mask, then exact top_k(masked,4)
        float mval; int pos = lane, srcb = 0, w8 = 0;
        if (lane < 8) {
            w8   = word;
            srcb = cj >> 3;
            const bool iseos = (w8 == eos) && (val > -INFINITY);
            mval = iseos ? -INFINITY : val;
        } else {
            mval = -INFINITY;
        }
#pragma unroll
        for (int k = 2; k <= 8; k <<= 1) {
#pragma unroll
            for (int j = k >> 1; j > 0; j >>= 1) {
                const float ov = __shfl_xor(mval, j, 64);
                const int   op = __shfl_xor(pos,  j, 64);
                const int   ob = __shfl_xor(srcb, j, 64);
                const int   ow = __shfl_xor(w8,   j, 64);
                const bool dirDesc   = ((lane & k) == 0);
                const bool iAmLow    = ((lane & j) == 0);
                const bool mineFirst = gtvi(mval, pos, ov, op);
                const bool takeOther = dirDesc ? (iAmLow ? !mineFirst : mineFirst)
                                               : (iAmLow ? mineFirst : !mineFirst);
                if (takeOther) { mval = ov; pos = op; srcb = ob; w8 = ow; }
            }
        }

        if (lane < 4) {
            s_sc[lane]    = mval;   // new cumulative scores (sel_scores)
            s_rb[t][lane] = srcb;   // source (old) beam
            s_rw[t][lane] = w8;     // chosen word
        }
        __syncthreads();
    }

    // Backtrace + output (d_out = [scores (128) | tokens (128*17)], f32)
    if (lane < BEAM) {
        out[b * BEAM + lane] = s_sc[lane];
        float* tout = out + BATCH * BEAM + (size_t)(b * BEAM + lane) * (T_STEPS + 1);
        int bp = lane;
#pragma unroll
        for (int t = T_STEPS - 1; t >= 0; --t) {
            tout[t + 1] = (float)s_rw[t][bp];
            bp = s_rb[t][bp];
        }
        tout[0] = (float)eos;   // begin token
    }
}

// ---------------------------------------------------------------------------
extern "C" void kernel_launch(void* const* d_in, const int* in_sizes, int n_in,
                              void* d_out, int out_size, void* d_ws, size_t ws_size,
                              hipStream_t stream) {
    const float* logits = (const float*)d_in[0];
    const int*   pad_p  = (const int*)d_in[1];
    const int*   unk_p  = (const int*)d_in[2];
    const int*   eos_p  = (const int*)d_in[3];
    // d_in[4] = beam_size (hardcoded 4 to match shapes)

    // Workspace layout (bytes):
    //   sv    [NROWS*CAP_S] f32   @ 0            (1,048,576)
    //   si    [NROWS*CAP_S] i32   @ 1,048,576    (1,048,576)
    //   cnt   [NROWS]       i32   @ 2,097,152    (8,192)   <- zeroed each call
    //   sums4 [NROWS*4]     f32   @ 2,105,344    (32,768)
    //   topv  [NROWS*8]     f32   @ 2,138,112    (65,536)
    //   topi  [NROWS*8]     i32   @ 2,203,648    (65,536)
    char* ws = (char*)d_ws;
    float* sv    = (float*)(ws + 0);
    int*   si    = (int*)  (ws + 1048576);
    int*   cnt   = (int*)  (ws + 2097152);
    float* sums4 = (float*)(ws + 2105344);
    float* topv  = (float*)(ws + 2138112);
    int*   topi  = (int*)  (ws + 2203648);

    hipMemsetAsync(cnt, 0, NROWS * sizeof(int), stream);

    hipLaunchKernelGGL(stream_scan, dim3(NROWS * 4), dim3(256), 0, stream,
                       logits, pad_p, unk_p, sv, si, cnt, sums4);
    hipLaunchKernelGGL(select_topk, dim3(NROWS), dim3(64), 0, stream,
                       logits, pad_p, unk_p, sv, si, cnt, sums4, topv, topi);
    hipLaunchKernelGGL(phase2_beam_scan, dim3(BATCH), dim3(64), 0, stream,
                       topv, topi, eos_p, (float*)d_out);
}